// Round 1
// baseline (93.488 us; speedup 1.0000x reference)
//
#include <hip/hip_runtime.h>
#include <math.h>

#define Bc 4
#define Cc 128
#define Dc 24
#define Hc 24
#define Wc 24
#define Pc 64

// One 8-lane group per (b,p,c). Each lane handles d = s0x + j, j+8, ...
// Separable register max over (w, h) with overlapping-region predicates,
// then shfl_xor max-reduce across the 8 lanes, lane 0 writes 8 outputs.
__global__ __launch_bounds__(256) void crop_pool_kernel(
    const float* __restrict__ fm, const int* __restrict__ corners,
    const int* __restrict__ scale_p, float* __restrict__ out)
{
    const int tid   = threadIdx.x;
    const int c_sub = tid >> 3;      // 0..31
    const int j     = tid & 7;       // 0..7
    const int blk   = blockIdx.x;    // = bp*4 + cgroup
    const int bp    = blk >> 2;      // 0..255  (b*P + p)
    const int cgrp  = blk & 3;
    const int b     = bp >> 6;       // P = 64
    const int c     = cgrp * 32 + c_sub;

    const int scale = scale_p[0];

    // Per-axis adaptive-pool bounds (k: 0->D, 1->H, 2->W)
    int s0[3], e0[3], s1[3], e1[3];
    const int sizes[3] = {Dc, Hc, Wc};
#pragma unroll
    for (int k = 0; k < 3; ++k) {
        int c0 = corners[(bp * 2 + 0) * 3 + k];
        int c1 = corners[(bp * 2 + 1) * 3 + k];
        int p1v = c0 / scale;                 // corners >= 0 so / == floor-div
        p1v = p1v < 0 ? 0 : (p1v > 21 ? 21 : p1v);
        int p2v = c1 / scale;
        if (p2v - p1v < 2) p2v = p1v + 2;
        int e = p2v < sizes[k] ? p2v : sizes[k];
        int n = e - p1v;                      // 2..23
        s0[k] = p1v;                          // region0 start
        e0[k] = p1v + ((n + 1) >> 1);         // region0 end
        s1[k] = p1v + (n >> 1);               // region1 start
        e1[k] = e;                            // region1 end (crop end)
    }

    const float* base = fm + ((size_t)(b * Cc + c)) * (Dc * Hc * Wc);

    float acc[8];
#pragma unroll
    for (int i = 0; i < 8; ++i) acc[i] = -INFINITY;

    for (int d = s0[0] + j; d < e1[0]; d += 8) {
        float a00 = -INFINITY, a01 = -INFINITY, a10 = -INFINITY, a11 = -INFINITY;
        const float* plane = base + d * (Hc * Wc);
        for (int h = s0[1]; h < e1[1]; ++h) {
            float w0 = -INFINITY, w1 = -INFINITY;
            const float* row = plane + h * Wc;
            for (int w = s0[2]; w < e1[2]; ++w) {
                float v = row[w];
                if (w < e0[2])  w0 = fmaxf(w0, v);
                if (w >= s1[2]) w1 = fmaxf(w1, v);
            }
            if (h < e0[1])  { a00 = fmaxf(a00, w0); a01 = fmaxf(a01, w1); }
            if (h >= s1[1]) { a10 = fmaxf(a10, w0); a11 = fmaxf(a11, w1); }
        }
        if (d < e0[0]) {
            acc[0] = fmaxf(acc[0], a00); acc[1] = fmaxf(acc[1], a01);
            acc[2] = fmaxf(acc[2], a10); acc[3] = fmaxf(acc[3], a11);
        }
        if (d >= s1[0]) {
            acc[4] = fmaxf(acc[4], a00); acc[5] = fmaxf(acc[5], a01);
            acc[6] = fmaxf(acc[6], a10); acc[7] = fmaxf(acc[7], a11);
        }
    }

    // Reduce across the 8 lanes of the group (consecutive lanes, masks 1/2/4)
#pragma unroll
    for (int off = 1; off < 8; off <<= 1) {
#pragma unroll
        for (int i = 0; i < 8; ++i)
            acc[i] = fmaxf(acc[i], __shfl_xor(acc[i], off));
    }

    if (j == 0) {
        float4* o = (float4*)(out + ((size_t)bp * Cc + c) * 8);
        o[0] = make_float4(acc[0], acc[1], acc[2], acc[3]);
        o[1] = make_float4(acc[4], acc[5], acc[6], acc[7]);
    }
}

extern "C" void kernel_launch(void* const* d_in, const int* in_sizes, int n_in,
                              void* d_out, int out_size, void* d_ws, size_t ws_size,
                              hipStream_t stream) {
    const float* fm      = (const float*)d_in[0];
    const int*   corners = (const int*)d_in[1];
    const int*   scale   = (const int*)d_in[2];
    float*       out     = (float*)d_out;

    dim3 grid(Bc * Pc * (Cc / 32));   // 1024 blocks
    dim3 block(256);
    crop_pool_kernel<<<grid, block, 0, stream>>>(fm, corners, scale, out);
}

// Round 2
// 67.890 us; speedup vs baseline: 1.3770x; 1.3770x over previous
//
#include <hip/hip_runtime.h>
#include <math.h>

#define Bc 4
#define Cc 128
#define Dc 24
#define Hc 24
#define Wc 24
#define Pc 64
#define PLANE (Hc * Wc)   // 576
#define VOL   (Dc * Hc * Wc)

// One wave (64 lanes) per (b,p,c). For each d-plane of the crop, the wave
// sweeps the contiguous segment of full h-rows [s_h,e_h) with float4 loads
// (64 lanes x 16B = 1KB contiguous per instruction). Region membership is
// resolved branchlessly per element; d-region bank select is a scalar branch
// (bounds forced to SGPR via readfirstlane). Final 64-lane shfl_xor reduce.
__global__ __launch_bounds__(256) void crop_pool_kernel(
    const float* __restrict__ fm, const int* __restrict__ corners,
    const int* __restrict__ scale_p, float* __restrict__ out)
{
    const int lane = threadIdx.x & 63;
    const int wid  = threadIdx.x >> 6;   // 0..3 (wave in block)
    const int bp   = blockIdx.x >> 5;    // 0..255  (b*P + p)
    const int cq   = blockIdx.x & 31;    // channel quad
    const int c    = cq * 4 + wid;       // 0..127
    const int b    = bp >> 6;            // P = 64

    const int scale = scale_p[0];

    // Per-axis bounds (k: 0->D, 1->H, 2->W), identical across lanes ->
    // force to SGPRs so control flow on them is scalar.
    int s[3], e[3], m0[3], m1[3];
#pragma unroll
    for (int k = 0; k < 3; ++k) {
        int c0 = corners[(bp * 2 + 0) * 3 + k];
        int c1 = corners[(bp * 2 + 1) * 3 + k];
        int p1v = c0 / scale;                 // corners >= 0 -> floor div
        p1v = p1v < 0 ? 0 : (p1v > 21 ? 21 : p1v);
        int p2v = c1 / scale;
        if (p2v - p1v < 2) p2v = p1v + 2;
        int ee = p2v < 24 ? p2v : 24;
        int n  = ee - p1v;                    // 2..23
        s[k]  = __builtin_amdgcn_readfirstlane(p1v);
        e[k]  = __builtin_amdgcn_readfirstlane(ee);
        m0[k] = __builtin_amdgcn_readfirstlane(p1v + ((n + 1) >> 1)); // region0 end
        m1[k] = __builtin_amdgcn_readfirstlane(p1v + (n >> 1));       // region1 start
    }

    const float* base = fm + ((size_t)(b * Cc + c)) * VOL;
    const int fstart = s[1] * Wc;   // first float of the h-row segment
    const int fend   = e[1] * Wc;   // one past last (multiple of 4)

    float a[8];
#pragma unroll
    for (int i = 0; i < 8; ++i) a[i] = -INFINITY;

    const int sw = s[2], ew = e[2], m0w = m0[2], m1w = m1[2];
    const int m0h = m0[1], m1h = m1[1];

    for (int d = s[0]; d < e[0]; ++d) {
        const float* plane = base + d * PLANE;
        float p00 = -INFINITY, p01 = -INFINITY, p10 = -INFINITY, p11 = -INFINITY;

        for (int f = fstart + lane * 4; f < fend; f += 256) {
            float4 v = *(const float4*)(plane + f);
            int h = (int)((unsigned)f / 24u);
            int w = f - h * 24;               // 24%4==0 -> float4 within one row
            bool h0 = h <  m0h;
            bool h1 = h >= m1h;
#define UPD(X, T)                                                          \
            {                                                              \
                int  wt = w + (T);                                         \
                bool w0 = (wt >= sw)  & (wt < m0w);                        \
                bool w1 = (wt >= m1w) & (wt < ew);                         \
                p00 = fmaxf(p00, (h0 & w0) ? (X) : -INFINITY);             \
                p01 = fmaxf(p01, (h0 & w1) ? (X) : -INFINITY);             \
                p10 = fmaxf(p10, (h1 & w0) ? (X) : -INFINITY);             \
                p11 = fmaxf(p11, (h1 & w1) ? (X) : -INFINITY);             \
            }
            UPD(v.x, 0) UPD(v.y, 1) UPD(v.z, 2) UPD(v.w, 3)
#undef UPD
        }

        if (d <  m0[0]) {   // scalar branch (bounds + d uniform)
            a[0] = fmaxf(a[0], p00); a[1] = fmaxf(a[1], p01);
            a[2] = fmaxf(a[2], p10); a[3] = fmaxf(a[3], p11);
        }
        if (d >= m1[0]) {
            a[4] = fmaxf(a[4], p00); a[5] = fmaxf(a[5], p01);
            a[6] = fmaxf(a[6], p10); a[7] = fmaxf(a[7], p11);
        }
    }

    // 64-lane butterfly max-reduce of the 8 octants
#pragma unroll
    for (int off = 32; off; off >>= 1) {
#pragma unroll
        for (int i = 0; i < 8; ++i)
            a[i] = fmaxf(a[i], __shfl_xor(a[i], off));
    }

    if (lane == 0) {
        float4* o = (float4*)(out + ((size_t)bp * Cc + c) * 8);
        o[0] = make_float4(a[0], a[1], a[2], a[3]);
        o[1] = make_float4(a[4], a[5], a[6], a[7]);
    }
}

extern "C" void kernel_launch(void* const* d_in, const int* in_sizes, int n_in,
                              void* d_out, int out_size, void* d_ws, size_t ws_size,
                              hipStream_t stream) {
    const float* fm      = (const float*)d_in[0];
    const int*   corners = (const int*)d_in[1];
    const int*   scale   = (const int*)d_in[2];
    float*       out     = (float*)d_out;

    dim3 grid(Bc * Pc * 32);   // 8192 blocks: one wave per (b,p,c)
    dim3 block(256);
    crop_pool_kernel<<<grid, block, 0, stream>>>(fm, corners, scale, out);
}

// Round 4
// 40.632 us; speedup vs baseline: 2.3008x; 1.6708x over previous
//
#include <hip/hip_runtime.h>
#include <math.h>

#define Bc 4
#define Cc 128
#define Dc 24
#define Hc 24
#define Wc 24
#define Pc 64
#define PLANE (Hc * Wc)   // 576
#define VOL   (Dc * Hc * Wc)

// One wave per (b,p,c). The h-row segment of a plane is up to 528 floats ->
// up to THREE float4 chunks per lane (f, f+256, f+512), each with
// d-invariant precomputed w-region biases (0/-inf) and h-masks. Chunk 1/2
// presence is wave-uniform -> scalar branch. d-region split = 3 uniform loop
// segments. Epilogue: per-chunk h-mask, merge to 8 octants, butterfly reduce.
__global__ __launch_bounds__(256) void crop_pool_kernel(
    const float* __restrict__ fm, const int* __restrict__ corners,
    const int* __restrict__ scale_p, float* __restrict__ out)
{
    const int lane = threadIdx.x & 63;
    const int wid  = threadIdx.x >> 6;   // 0..3
    const int bp   = blockIdx.x & 255;   // interleave proposals across blocks
    const int cq   = blockIdx.x >> 8;    // 0..31
    const int c    = cq * 4 + wid;
    const int b    = bp >> 6;            // P = 64

    const int scale = scale_p[0];

    // Per-axis bounds (k: 0->D, 1->H, 2->W), uniform -> SGPR.
    int s[3], e[3], m0[3], m1[3];
#pragma unroll
    for (int k = 0; k < 3; ++k) {
        int c0 = corners[(bp * 2 + 0) * 3 + k];
        int c1 = corners[(bp * 2 + 1) * 3 + k];
        int p1v = c0 / scale;                 // corners >= 0 -> floor div
        p1v = p1v < 0 ? 0 : (p1v > 21 ? 21 : p1v);
        int p2v = c1 / scale;
        if (p2v - p1v < 2) p2v = p1v + 2;
        int ee = p2v < 24 ? p2v : 24;
        int n  = ee - p1v;                    // 2..23
        s[k]  = __builtin_amdgcn_readfirstlane(p1v);
        e[k]  = __builtin_amdgcn_readfirstlane(ee);
        m0[k] = __builtin_amdgcn_readfirstlane(p1v + ((n + 1) >> 1)); // r0 end
        m1[k] = __builtin_amdgcn_readfirstlane(p1v + (n >> 1));       // r1 start
    }

    const float* base = fm + ((size_t)(b * Cc + c)) * VOL;
    const int fstart = s[1] * Wc;            // multiple of 4 (Wc = 24)
    const int fend   = e[1] * Wc;
    const int seglen = fend - fstart;        // <= 528

    const bool c1p = seglen > 256;           // wave-uniform chunk presence
    const bool c2p = seglen > 512;

    const float NI = -INFINITY;
    const int sw = s[2], ew = e[2], m0w = m0[2], m1w = m1[2];
    const int m0h = m0[1], m1h = m1[1];

    // Per-chunk d-invariant state: load offset, h-masks, w-biases, 4 accs.
#define SETUP(K)                                                            \
    const int  f_##K   = fstart + lane * 4 + (K) * 256;                     \
    const int  fcl_##K = f_##K < (PLANE - 4) ? f_##K : (PLANE - 4);         \
    const bool va_##K  = f_##K < fend;                                      \
    const int  h_##K   = (int)((unsigned)f_##K / 24u);                      \
    const int  w_##K   = f_##K - h_##K * 24;                                \
    const bool h0_##K  = h_##K <  m0h;                                      \
    const bool h1_##K  = h_##K >= m1h;                                      \
    float b0x_##K, b0y_##K, b0z_##K, b0w_##K;                               \
    float b1x_##K, b1y_##K, b1z_##K, b1w_##K;                               \
    {                                                                       \
        int wt;                                                             \
        wt = w_##K + 0;                                                     \
        b0x_##K = (va_##K && wt >= sw  && wt < m0w) ? 0.0f : NI;            \
        b1x_##K = (va_##K && wt >= m1w && wt < ew ) ? 0.0f : NI;            \
        wt = w_##K + 1;                                                     \
        b0y_##K = (va_##K && wt >= sw  && wt < m0w) ? 0.0f : NI;            \
        b1y_##K = (va_##K && wt >= m1w && wt < ew ) ? 0.0f : NI;            \
        wt = w_##K + 2;                                                     \
        b0z_##K = (va_##K && wt >= sw  && wt < m0w) ? 0.0f : NI;            \
        b1z_##K = (va_##K && wt >= m1w && wt < ew ) ? 0.0f : NI;            \
        wt = w_##K + 3;                                                     \
        b0w_##K = (va_##K && wt >= sw  && wt < m0w) ? 0.0f : NI;            \
        b1w_##K = (va_##K && wt >= m1w && wt < ew ) ? 0.0f : NI;            \
    }                                                                       \
    float a00_##K = NI, a01_##K = NI, a10_##K = NI, a11_##K = NI;

    SETUP(0)
    SETUP(1)
    SETUP(2)
#undef SETUP

    // Per-plane per-chunk: 1 float4 load + 8 add + 6 max, then acc updates.
#define CHUNK_T(K)                                                          \
        float4 v_##K = *(const float4*)(pplane + fcl_##K);                  \
        float t0_##K = fmaxf(fmaxf(v_##K.x + b0x_##K, v_##K.y + b0y_##K),   \
                             fmaxf(v_##K.z + b0z_##K, v_##K.w + b0w_##K));  \
        float t1_##K = fmaxf(fmaxf(v_##K.x + b1x_##K, v_##K.y + b1y_##K),   \
                             fmaxf(v_##K.z + b1z_##K, v_##K.w + b1w_##K));

#define UPD_R0(K)  a00_##K = fmaxf(a00_##K, t0_##K);                        \
                   a01_##K = fmaxf(a01_##K, t1_##K);
#define UPD_R1(K)  a10_##K = fmaxf(a10_##K, t0_##K);                        \
                   a11_##K = fmaxf(a11_##K, t1_##K);

#define BODY(UPDM)                                                          \
    {                                                                       \
        const float* pplane = base + d * PLANE;                             \
        { CHUNK_T(0) UPDM(0) }                                              \
        if (c1p) { CHUNK_T(1) UPDM(1) }                                     \
        if (c2p) { CHUNK_T(2) UPDM(2) }                                     \
    }
#define UPD_BOTH(K) UPD_R0(K) UPD_R1(K)

    int d = s[0];
    for (; d < m1[0]; ++d) BODY(UPD_R0)     // d-region 0 only
    for (; d < m0[0]; ++d) BODY(UPD_BOTH)   // overlap (n_d odd)
    for (; d < e[0];  ++d) BODY(UPD_R1)     // d-region 1 only
#undef BODY
#undef UPD_BOTH
#undef UPD_R0
#undef UPD_R1
#undef CHUNK_T

    // Merge chunks: apply per-chunk h-masks into 8 octants [dr][hr][wr].
    float o[8];
#pragma unroll
    for (int i = 0; i < 8; ++i) o[i] = NI;
#define MERGE(K)                                                            \
    o[0] = fmaxf(o[0], h0_##K ? a00_##K : NI);                              \
    o[1] = fmaxf(o[1], h0_##K ? a01_##K : NI);                              \
    o[2] = fmaxf(o[2], h1_##K ? a00_##K : NI);                              \
    o[3] = fmaxf(o[3], h1_##K ? a01_##K : NI);                              \
    o[4] = fmaxf(o[4], h0_##K ? a10_##K : NI);                              \
    o[5] = fmaxf(o[5], h0_##K ? a11_##K : NI);                              \
    o[6] = fmaxf(o[6], h1_##K ? a10_##K : NI);                              \
    o[7] = fmaxf(o[7], h1_##K ? a11_##K : NI);
    MERGE(0)
    MERGE(1)
    MERGE(2)
#undef MERGE

    // 64-lane butterfly max-reduce of the 8 octants
#pragma unroll
    for (int off = 32; off; off >>= 1) {
#pragma unroll
        for (int i = 0; i < 8; ++i)
            o[i] = fmaxf(o[i], __shfl_xor(o[i], off));
    }

    if (lane == 0) {
        float4* op = (float4*)(out + ((size_t)bp * Cc + c) * 8);
        op[0] = make_float4(o[0], o[1], o[2], o[3]);
        op[1] = make_float4(o[4], o[5], o[6], o[7]);
    }
}

extern "C" void kernel_launch(void* const* d_in, const int* in_sizes, int n_in,
                              void* d_out, int out_size, void* d_ws, size_t ws_size,
                              hipStream_t stream) {
    const float* fm      = (const float*)d_in[0];
    const int*   corners = (const int*)d_in[1];
    const int*   scale   = (const int*)d_in[2];
    float*       out     = (float*)d_out;

    dim3 grid(Bc * Pc * 32);   // 8192 blocks: one wave per (b,p,c)
    dim3 block(256);
    crop_pool_kernel<<<grid, block, 0, stream>>>(fm, corners, scale, out);
}

// Round 5
// 32.090 us; speedup vs baseline: 2.9133x; 1.2662x over previous
//
#include <hip/hip_runtime.h>
#include <math.h>

#define Bc 4
#define Cc 128
#define Dc 24
#define Hc 24
#define Wc 24
#define Pc 64
#define PLANE (Hc * Wc)   // 576
#define VOL   (Dc * Hc * Wc)

// One wave per (b,p,c). Up to three d-invariant float4 chunks per lane with
// precomputed w-region biases (0/-inf) and h-masks; d-region split = 3
// uniform scalar loop segments; epilogue h-mask + butterfly reduce.
// Block mapping: bp = blockIdx>>5 so a proposal's 32 blocks are CONSECUTIVE
// -> spread across 8 XCDs x 4 CUs (stride-256 mapping put all 128 waves of
// the heaviest proposal on ONE CU -> ~57us serial tail).
__global__ __launch_bounds__(256) void crop_pool_kernel(
    const float* __restrict__ fm, const int* __restrict__ corners,
    const int* __restrict__ scale_p, float* __restrict__ out)
{
    const int lane = threadIdx.x & 63;
    const int wid  = threadIdx.x >> 6;   // 0..3
    const int bp   = blockIdx.x >> 5;    // 0..255 (b*P + p) — consecutive blocks share bp
    const int cq   = blockIdx.x & 31;    // channel quad group
    const int c    = cq * 4 + wid;
    const int b    = bp >> 6;            // P = 64

    const int scale = scale_p[0];

    // Per-axis bounds (k: 0->D, 1->H, 2->W), uniform -> SGPR.
    int s[3], e[3], m0[3], m1[3];
#pragma unroll
    for (int k = 0; k < 3; ++k) {
        int c0 = corners[(bp * 2 + 0) * 3 + k];
        int c1 = corners[(bp * 2 + 1) * 3 + k];
        int p1v = c0 / scale;                 // corners >= 0 -> floor div
        p1v = p1v < 0 ? 0 : (p1v > 21 ? 21 : p1v);
        int p2v = c1 / scale;
        if (p2v - p1v < 2) p2v = p1v + 2;
        int ee = p2v < 24 ? p2v : 24;
        int n  = ee - p1v;                    // 2..23
        s[k]  = __builtin_amdgcn_readfirstlane(p1v);
        e[k]  = __builtin_amdgcn_readfirstlane(ee);
        m0[k] = __builtin_amdgcn_readfirstlane(p1v + ((n + 1) >> 1)); // r0 end
        m1[k] = __builtin_amdgcn_readfirstlane(p1v + (n >> 1));       // r1 start
    }

    const float* base = fm + ((size_t)(b * Cc + c)) * VOL;
    const int fstart = s[1] * Wc;            // multiple of 4 (Wc = 24)
    const int fend   = e[1] * Wc;
    const int seglen = fend - fstart;        // <= 528

    const bool c1p = seglen > 256;           // wave-uniform chunk presence
    const bool c2p = seglen > 512;

    const float NI = -INFINITY;
    const int sw = s[2], ew = e[2], m0w = m0[2], m1w = m1[2];
    const int m0h = m0[1], m1h = m1[1];

    // Per-chunk d-invariant state: load offset, h-masks, w-biases, 4 accs.
#define SETUP(K)                                                            \
    const int  f_##K   = fstart + lane * 4 + (K) * 256;                     \
    const int  fcl_##K = f_##K < (PLANE - 4) ? f_##K : (PLANE - 4);         \
    const bool va_##K  = f_##K < fend;                                      \
    const int  h_##K   = (int)((unsigned)f_##K / 24u);                      \
    const int  w_##K   = f_##K - h_##K * 24;                                \
    const bool h0_##K  = h_##K <  m0h;                                      \
    const bool h1_##K  = h_##K >= m1h;                                      \
    float b0x_##K, b0y_##K, b0z_##K, b0w_##K;                               \
    float b1x_##K, b1y_##K, b1z_##K, b1w_##K;                               \
    {                                                                       \
        int wt;                                                             \
        wt = w_##K + 0;                                                     \
        b0x_##K = (va_##K && wt >= sw  && wt < m0w) ? 0.0f : NI;            \
        b1x_##K = (va_##K && wt >= m1w && wt < ew ) ? 0.0f : NI;            \
        wt = w_##K + 1;                                                     \
        b0y_##K = (va_##K && wt >= sw  && wt < m0w) ? 0.0f : NI;            \
        b1y_##K = (va_##K && wt >= m1w && wt < ew ) ? 0.0f : NI;            \
        wt = w_##K + 2;                                                     \
        b0z_##K = (va_##K && wt >= sw  && wt < m0w) ? 0.0f : NI;            \
        b1z_##K = (va_##K && wt >= m1w && wt < ew ) ? 0.0f : NI;            \
        wt = w_##K + 3;                                                     \
        b0w_##K = (va_##K && wt >= sw  && wt < m0w) ? 0.0f : NI;            \
        b1w_##K = (va_##K && wt >= m1w && wt < ew ) ? 0.0f : NI;            \
    }                                                                       \
    float a00_##K = NI, a01_##K = NI, a10_##K = NI, a11_##K = NI;

    SETUP(0)
    SETUP(1)
    SETUP(2)
#undef SETUP

#define CHUNK_T(K)                                                          \
        float4 v_##K = *(const float4*)(pplane + fcl_##K);                  \
        float t0_##K = fmaxf(fmaxf(v_##K.x + b0x_##K, v_##K.y + b0y_##K),   \
                             fmaxf(v_##K.z + b0z_##K, v_##K.w + b0w_##K));  \
        float t1_##K = fmaxf(fmaxf(v_##K.x + b1x_##K, v_##K.y + b1y_##K),   \
                             fmaxf(v_##K.z + b1z_##K, v_##K.w + b1w_##K));

#define UPD_R0(K)  a00_##K = fmaxf(a00_##K, t0_##K);                        \
                   a01_##K = fmaxf(a01_##K, t1_##K);
#define UPD_R1(K)  a10_##K = fmaxf(a10_##K, t0_##K);                        \
                   a11_##K = fmaxf(a11_##K, t1_##K);

#define BODY(UPDM)                                                          \
    {                                                                       \
        { CHUNK_T(0) UPDM(0) }                                              \
        if (c1p) { CHUNK_T(1) UPDM(1) }                                     \
        if (c2p) { CHUNK_T(2) UPDM(2) }                                     \
        pplane += PLANE;                                                    \
    }
#define UPD_BOTH(K) UPD_R0(K) UPD_R1(K)

    const float* pplane = base + (size_t)s[0] * PLANE;
    int d = s[0];
    for (; d < m1[0]; ++d) BODY(UPD_R0)     // d-region 0 only
    for (; d < m0[0]; ++d) BODY(UPD_BOTH)   // overlap (n_d odd)
    for (; d < e[0];  ++d) BODY(UPD_R1)     // d-region 1 only
#undef BODY
#undef UPD_BOTH
#undef UPD_R0
#undef UPD_R1
#undef CHUNK_T

    // Merge chunks: apply per-chunk h-masks into 8 octants [dr][hr][wr].
    float o[8];
#pragma unroll
    for (int i = 0; i < 8; ++i) o[i] = NI;
#define MERGE(K)                                                            \
    o[0] = fmaxf(o[0], h0_##K ? a00_##K : NI);                              \
    o[1] = fmaxf(o[1], h0_##K ? a01_##K : NI);                              \
    o[2] = fmaxf(o[2], h1_##K ? a00_##K : NI);                              \
    o[3] = fmaxf(o[3], h1_##K ? a01_##K : NI);                              \
    o[4] = fmaxf(o[4], h0_##K ? a10_##K : NI);                              \
    o[5] = fmaxf(o[5], h0_##K ? a11_##K : NI);                              \
    o[6] = fmaxf(o[6], h1_##K ? a10_##K : NI);                              \
    o[7] = fmaxf(o[7], h1_##K ? a11_##K : NI);
    MERGE(0)
    MERGE(1)
    MERGE(2)
#undef MERGE

    // 64-lane butterfly max-reduce of the 8 octants
#pragma unroll
    for (int off = 32; off; off >>= 1) {
#pragma unroll
        for (int i = 0; i < 8; ++i)
            o[i] = fmaxf(o[i], __shfl_xor(o[i], off));
    }

    if (lane == 0) {
        float4* op = (float4*)(out + ((size_t)bp * Cc + c) * 8);
        op[0] = make_float4(o[0], o[1], o[2], o[3]);
        op[1] = make_float4(o[4], o[5], o[6], o[7]);
    }
}

extern "C" void kernel_launch(void* const* d_in, const int* in_sizes, int n_in,
                              void* d_out, int out_size, void* d_ws, size_t ws_size,
                              hipStream_t stream) {
    const float* fm      = (const float*)d_in[0];
    const int*   corners = (const int*)d_in[1];
    const int*   scale   = (const int*)d_in[2];
    float*       out     = (float*)d_out;

    dim3 grid(Bc * Pc * 32);   // 8192 blocks: one wave per (b,p,c)
    dim3 block(256);
    crop_pool_kernel<<<grid, block, 0, stream>>>(fm, corners, scale, out);
}

// Round 6
// 30.591 us; speedup vs baseline: 3.0560x; 1.0490x over previous
//
#include <hip/hip_runtime.h>
#include <math.h>

#define Bc 4
#define Cc 128
#define Pc 64
#define PLANE 576      // 24*24
#define VOL   13824    // 24^3

// One wave per (b,p,c). Lane -> (row r=lane/Q, quad q=lane%Q) where Q = number
// of 4-float quads spanning the w-crop (1..7) and R=64/Q rows per sweep: loads
// only touch the cropped w-range (vs full 24-wide rows). Up to 3 row-chunks
// (R>=9, n_h<=23), each with d-invariant biases (0/-inf, validity folded) and
// h-masks. Duplicated rows across chunks are harmless (max idempotent).
// d-region split = 3 uniform scalar segments, main ones unrolled x2 so two
// planes' loads are in flight (latency hiding). Epilogue: h-mask merge to 8
// octants + 64-lane butterfly; lane 0 writes 2 float4.

struct ChunkState {
    int   fcl;                       // clamped in-plane load offset (4-aligned)
    float b0x, b0y, b0z, b0w;        // region-0 w-biases (0 or -inf)
    float b1x, b1y, b1z, b1w;        // region-1 w-biases
    bool  h0, h1;                    // h-region membership of this lane's row
};

struct TV { float t0, t1; };

__device__ __forceinline__ TV eval_chunk(const float* __restrict__ p,
                                         const ChunkState& cs) {
    float4 v = *(const float4*)(p + cs.fcl);
    TV r;
    r.t0 = fmaxf(fmaxf(v.x + cs.b0x, v.y + cs.b0y),
                 fmaxf(v.z + cs.b0z, v.w + cs.b0w));
    r.t1 = fmaxf(fmaxf(v.x + cs.b1x, v.y + cs.b1y),
                 fmaxf(v.z + cs.b1z, v.w + cs.b1w));
    return r;
}

__global__ __launch_bounds__(256) void crop_pool_kernel(
    const float* __restrict__ fm, const int* __restrict__ corners,
    const int* __restrict__ scale_p, float* __restrict__ out)
{
    const int lane = threadIdx.x & 63;
    const int wid  = threadIdx.x >> 6;   // 0..3
    const int bp   = blockIdx.x >> 5;    // consecutive blocks share a proposal
    const int cq   = blockIdx.x & 31;
    const int c    = cq * 4 + wid;
    const int b    = bp >> 6;            // P = 64

    const int scale = scale_p[0];

    // Per-axis bounds (k: 0->D, 1->H, 2->W), uniform -> SGPR.
    int s[3], e[3], m0[3], m1[3];
#pragma unroll
    for (int k = 0; k < 3; ++k) {
        int c0 = corners[(bp * 2 + 0) * 3 + k];
        int c1 = corners[(bp * 2 + 1) * 3 + k];
        int p1v = c0 / scale;                 // corners >= 0 -> floor div
        p1v = p1v < 0 ? 0 : (p1v > 21 ? 21 : p1v);
        int p2v = c1 / scale;
        if (p2v - p1v < 2) p2v = p1v + 2;
        int ee = p2v < 24 ? p2v : 24;
        int n  = ee - p1v;                    // 2..23
        s[k]  = __builtin_amdgcn_readfirstlane(p1v);
        e[k]  = __builtin_amdgcn_readfirstlane(ee);
        m0[k] = __builtin_amdgcn_readfirstlane(p1v + ((n + 1) >> 1)); // r0 end
        m1[k] = __builtin_amdgcn_readfirstlane(p1v + (n >> 1));       // r1 start
    }

    const int sh  = s[1], nh = e[1] - s[1];
    const int m0h = m0[1], m1h = m1[1];
    const int sw  = s[2], ew = e[2], m0w = m0[2], m1w = m1[2];

    const int qb = sw & ~3;                            // aligned w base
    const int Q  = ((sw & 3) + (ew - sw) + 3) >> 2;    // quads per row, 1..7
    const int R  = 64 / Q;                             // rows per sweep, >= 9

    // lane/Q via exact magic multiply (Q<=7, lane<=63 verified)
    const unsigned M = (65536u + (unsigned)Q - 1) / (unsigned)Q;
    const int r = (int)(((unsigned)lane * M) >> 16);
    const int q = lane - r * Q;
    const int wbase = qb + 4 * q;

    const bool c1p = nh > R;                 // wave-uniform chunk presence
    const bool c2p = nh > 2 * R;

    const float NI = -INFINITY;

    ChunkState cs[3];
#pragma unroll
    for (int K = 0; K < 3; ++K) {
        const int  hrow = K * R + r;
        const int  h    = sh + hrow;
        const bool va   = hrow < nh;
        const int  f    = h * 24 + wbase;
        cs[K].fcl = f < (PLANE - 4) ? f : (PLANE - 4);
        cs[K].h0  = h <  m0h;
        cs[K].h1  = h >= m1h;
        int wt;
        wt = wbase + 0;
        cs[K].b0x = (va && wt >= sw  && wt < m0w) ? 0.0f : NI;
        cs[K].b1x = (va && wt >= m1w && wt < ew ) ? 0.0f : NI;
        wt = wbase + 1;
        cs[K].b0y = (va && wt >= sw  && wt < m0w) ? 0.0f : NI;
        cs[K].b1y = (va && wt >= m1w && wt < ew ) ? 0.0f : NI;
        wt = wbase + 2;
        cs[K].b0z = (va && wt >= sw  && wt < m0w) ? 0.0f : NI;
        cs[K].b1z = (va && wt >= m1w && wt < ew ) ? 0.0f : NI;
        wt = wbase + 3;
        cs[K].b0w = (va && wt >= sw  && wt < m0w) ? 0.0f : NI;
        cs[K].b1w = (va && wt >= m1w && wt < ew ) ? 0.0f : NI;
    }

    float a00[3], a01[3], a10[3], a11[3];
#pragma unroll
    for (int K = 0; K < 3; ++K) { a00[K]=NI; a01[K]=NI; a10[K]=NI; a11[K]=NI; }

#define UPD0(K, t) { a00[K] = fmaxf(a00[K], (t).t0); a01[K] = fmaxf(a01[K], (t).t1); }
#define UPD1(K, t) { a10[K] = fmaxf(a10[K], (t).t0); a11[K] = fmaxf(a11[K], (t).t1); }
#define UPDB(K, t) { UPD0(K, t) UPD1(K, t) }

#define STEP(UPD) {                                                         \
        { TV t = eval_chunk(pd, cs[0]); UPD(0, t); }                        \
        if (c1p) { TV t = eval_chunk(pd, cs[1]); UPD(1, t); }               \
        if (c2p) { TV t = eval_chunk(pd, cs[2]); UPD(2, t); }               \
        pd += PLANE; }

#define STEP2(UPD) {                                                        \
        const float* pA = pd; const float* pB = pd + PLANE;                 \
        { TV tA = eval_chunk(pA, cs[0]); TV tB = eval_chunk(pB, cs[0]);     \
          UPD(0, tA); UPD(0, tB); }                                         \
        if (c1p) { TV tA = eval_chunk(pA, cs[1]); TV tB = eval_chunk(pB, cs[1]); \
                   UPD(1, tA); UPD(1, tB); }                                \
        if (c2p) { TV tA = eval_chunk(pA, cs[2]); TV tB = eval_chunk(pB, cs[2]); \
                   UPD(2, tA); UPD(2, tB); }                                \
        pd += 2 * PLANE; }

    const float* pd = fm + ((size_t)(b * Cc + c)) * VOL + (size_t)s[0] * PLANE;
    int d = s[0];
    for (; d + 2 <= m1[0]; d += 2) STEP2(UPD0)   // d-region 0 only
    for (; d < m1[0]; ++d)         STEP(UPD0)
    for (; d < m0[0]; ++d)         STEP(UPDB)    // overlap plane (n_d odd)
    for (; d + 2 <= e[0]; d += 2)  STEP2(UPD1)   // d-region 1 only
    for (; d < e[0]; ++d)          STEP(UPD1)

#undef STEP2
#undef STEP
#undef UPDB
#undef UPD1
#undef UPD0

    // Merge chunks with per-lane h-masks into 8 octants [dr][hr][wr].
    float o[8];
#pragma unroll
    for (int i = 0; i < 8; ++i) o[i] = NI;
#pragma unroll
    for (int K = 0; K < 3; ++K) {
        o[0] = fmaxf(o[0], cs[K].h0 ? a00[K] : NI);
        o[1] = fmaxf(o[1], cs[K].h0 ? a01[K] : NI);
        o[2] = fmaxf(o[2], cs[K].h1 ? a00[K] : NI);
        o[3] = fmaxf(o[3], cs[K].h1 ? a01[K] : NI);
        o[4] = fmaxf(o[4], cs[K].h0 ? a10[K] : NI);
        o[5] = fmaxf(o[5], cs[K].h0 ? a11[K] : NI);
        o[6] = fmaxf(o[6], cs[K].h1 ? a10[K] : NI);
        o[7] = fmaxf(o[7], cs[K].h1 ? a11[K] : NI);
    }

    // 64-lane butterfly max-reduce of the 8 octants
#pragma unroll
    for (int off = 32; off; off >>= 1) {
#pragma unroll
        for (int i = 0; i < 8; ++i)
            o[i] = fmaxf(o[i], __shfl_xor(o[i], off));
    }

    if (lane == 0) {
        float4* op = (float4*)(out + ((size_t)bp * Cc + c) * 8);
        op[0] = make_float4(o[0], o[1], o[2], o[3]);
        op[1] = make_float4(o[4], o[5], o[6], o[7]);
    }
}

extern "C" void kernel_launch(void* const* d_in, const int* in_sizes, int n_in,
                              void* d_out, int out_size, void* d_ws, size_t ws_size,
                              hipStream_t stream) {
    const float* fm      = (const float*)d_in[0];
    const int*   corners = (const int*)d_in[1];
    const int*   scale   = (const int*)d_in[2];
    float*       out     = (float*)d_out;

    dim3 grid(Bc * Pc * 32);   // 8192 blocks: one wave per (b,p,c)
    dim3 block(256);
    crop_pool_kernel<<<grid, block, 0, stream>>>(fm, corners, scale, out);
}

// Round 7
// 21.699 us; speedup vs baseline: 4.3084x; 1.4098x over previous
//
#include <hip/hip_runtime.h>
#include <math.h>

#define Bc 4
#define Cc 128
#define Pc 64
#define PLANE 576      // 24*24
#define VOL   13824    // 24^3
#define NI    (-INFINITY)

// One wave per (proposal, channel-PAIR {c, c+64}): bounds/bias/loop control
// amortized over 2 channel streams. floor(c/scale) via uniform float
// reciprocal (exact: fraction >= 1/96 >> fp32 err). Chunks 1/2 set up and
// merged lazily (wave-uniform branch; rare). Epilogue: select-exchange
// reduce (octant bit -> lane bit, 8->4->2->1) + 3-step butterfly, ~34 ops
// per channel vs 96 for the plain 8-value butterfly; lanes 0..15 store.

struct ChunkState {
    int   fcl;                       // clamped in-plane load offset (4-aligned)
    float b0x, b0y, b0z, b0w;        // region-0 w-biases (0 or -inf)
    float b1x, b1y, b1z, b1w;        // region-1 w-biases
    bool  h0, h1;                    // h-region membership of this lane's row
};

__device__ __forceinline__ void eval2(const float* __restrict__ pA,
                                      const float* __restrict__ pB,
                                      const ChunkState& cs,
                                      float& t0A, float& t1A,
                                      float& t0B, float& t1B) {
    float4 a = *(const float4*)(pA + cs.fcl);
    float4 b = *(const float4*)(pB + cs.fcl);
    t0A = fmaxf(fmaxf(a.x + cs.b0x, a.y + cs.b0y), fmaxf(a.z + cs.b0z, a.w + cs.b0w));
    t1A = fmaxf(fmaxf(a.x + cs.b1x, a.y + cs.b1y), fmaxf(a.z + cs.b1z, a.w + cs.b1w));
    t0B = fmaxf(fmaxf(b.x + cs.b0x, b.y + cs.b0y), fmaxf(b.z + cs.b0z, b.w + cs.b0w));
    t1B = fmaxf(fmaxf(b.x + cs.b1x, b.y + cs.b1y), fmaxf(b.z + cs.b1z, b.w + cs.b1w));
}

// o[j] = candidate max for octant j (j = dr*4 + hr*2 + wr) on this lane.
// Returns octant (lane&7)'s max over all 64 lanes (identical across groups).
__device__ __forceinline__ float oct_reduce(const float o[8], int lane) {
    const bool b0 = lane & 1, b1 = lane & 2, b2 = lane & 4;
    float m0 = fmaxf(b0 ? o[1] : o[0], __shfl_xor(b0 ? o[0] : o[1], 1));
    float m1 = fmaxf(b0 ? o[3] : o[2], __shfl_xor(b0 ? o[2] : o[3], 1));
    float m2 = fmaxf(b0 ? o[5] : o[4], __shfl_xor(b0 ? o[4] : o[5], 1));
    float m3 = fmaxf(b0 ? o[7] : o[6], __shfl_xor(b0 ? o[6] : o[7], 1));
    float n0 = fmaxf(b1 ? m1 : m0, __shfl_xor(b1 ? m0 : m1, 2));
    float n1 = fmaxf(b1 ? m3 : m2, __shfl_xor(b1 ? m2 : m3, 2));
    float v  = fmaxf(b2 ? n1 : n0, __shfl_xor(b2 ? n0 : n1, 4));
    v = fmaxf(v, __shfl_xor(v, 8));
    v = fmaxf(v, __shfl_xor(v, 16));
    v = fmaxf(v, __shfl_xor(v, 32));
    return v;
}

__global__ __launch_bounds__(256) void crop_pool_kernel(
    const float* __restrict__ fm, const int* __restrict__ corners,
    const int* __restrict__ scale_p, float* __restrict__ out)
{
    const int lane = threadIdx.x & 63;
    const int wid  = threadIdx.x >> 6;   // 0..3
    const int bp   = blockIdx.x >> 4;    // 16 consecutive blocks per proposal
    const int cg   = blockIdx.x & 15;
    const int slot = cg * 4 + wid;       // 0..63
    const int cA   = slot;
    const int cB   = slot + 64;
    const int b    = bp >> 6;            // P = 64

    const float inv = 1.0f / (float)scale_p[0];   // uniform; exact-floor mul

    // Per-axis bounds (k: 0->D, 1->H, 2->W), uniform -> SGPR.
    int s[3], e[3], m0a[3], m1a[3];
#pragma unroll
    for (int k = 0; k < 3; ++k) {
        int c0 = corners[(bp * 2 + 0) * 3 + k];
        int c1 = corners[(bp * 2 + 1) * 3 + k];
        int p1v = (int)((float)c0 * inv);     // == c0/scale (c0 in [0,95])
        p1v = p1v > 21 ? 21 : p1v;
        int p2v = (int)((float)c1 * inv);
        if (p2v - p1v < 2) p2v = p1v + 2;
        int ee = p2v < 24 ? p2v : 24;
        int n  = ee - p1v;                    // 2..23
        s[k]   = __builtin_amdgcn_readfirstlane(p1v);
        e[k]   = __builtin_amdgcn_readfirstlane(ee);
        m0a[k] = __builtin_amdgcn_readfirstlane(p1v + ((n + 1) >> 1)); // r0 end
        m1a[k] = __builtin_amdgcn_readfirstlane(p1v + (n >> 1));       // r1 start
    }

    const int sh  = s[1], nh = e[1] - s[1];
    const int m0h = m0a[1], m1h = m1a[1];
    const int sw  = s[2], ew = e[2], m0w = m0a[2], m1w = m1a[2];

    const int qb = sw & ~3;                            // aligned w base
    const int Q  = ((sw & 3) + (ew - sw) + 3) >> 2;    // quads per row, 1..7
    const int R  = 64 / Q;                             // rows per sweep, >= 9

    // lane/Q via exact magic multiply (Q<=7, lane<=63)
    const unsigned M = (65536u + (unsigned)Q - 1) / (unsigned)Q;
    const int r = (int)(((unsigned)lane * M) >> 16);
    const int q = lane - r * Q;
    const int wbase = qb + 4 * q;                      // 4-aligned, <= 20

    const bool c1p = nh > R;                 // wave-uniform chunk presence
    const bool c2p = nh > 2 * R;

    ChunkState cs[3];
    float aA00[3], aA01[3], aA10[3], aA11[3];
    float aB00[3], aB01[3], aB10[3], aB11[3];
#pragma unroll
    for (int K = 0; K < 3; ++K) {
        aA00[K]=NI; aA01[K]=NI; aA10[K]=NI; aA11[K]=NI;
        aB00[K]=NI; aB01[K]=NI; aB10[K]=NI; aB11[K]=NI;
    }

#define SETUP(K) {                                                          \
        const int  hrow = (K) * R + r;                                      \
        const int  h    = sh + hrow;                                        \
        const bool va   = hrow < nh;                                        \
        const int  f    = h * 24 + wbase;                                   \
        cs[K].fcl = f < (PLANE - 4) ? f : (PLANE - 4);                      \
        cs[K].h0  = h <  m0h;                                               \
        cs[K].h1  = h >= m1h;                                               \
        int wt;                                                             \
        wt = wbase + 0;                                                     \
        cs[K].b0x = (va && wt >= sw  && wt < m0w) ? 0.0f : NI;              \
        cs[K].b1x = (va && wt >= m1w && wt < ew ) ? 0.0f : NI;              \
        wt = wbase + 1;                                                     \
        cs[K].b0y = (va && wt >= sw  && wt < m0w) ? 0.0f : NI;              \
        cs[K].b1y = (va && wt >= m1w && wt < ew ) ? 0.0f : NI;              \
        wt = wbase + 2;                                                     \
        cs[K].b0z = (va && wt >= sw  && wt < m0w) ? 0.0f : NI;              \
        cs[K].b1z = (va && wt >= m1w && wt < ew ) ? 0.0f : NI;              \
        wt = wbase + 3;                                                     \
        cs[K].b0w = (va && wt >= sw  && wt < m0w) ? 0.0f : NI;              \
        cs[K].b1w = (va && wt >= m1w && wt < ew ) ? 0.0f : NI;              \
    }

    SETUP(0)
    if (c1p) SETUP(1)
    if (c2p) SETUP(2)
#undef SETUP

#define UPD0(K) { aA00[K]=fmaxf(aA00[K],t0A); aA01[K]=fmaxf(aA01[K],t1A);   \
                  aB00[K]=fmaxf(aB00[K],t0B); aB01[K]=fmaxf(aB01[K],t1B); }
#define UPD1(K) { aA10[K]=fmaxf(aA10[K],t0A); aA11[K]=fmaxf(aA11[K],t1A);   \
                  aB10[K]=fmaxf(aB10[K],t0B); aB11[K]=fmaxf(aB11[K],t1B); }
#define UPDB(K) UPD0(K) UPD1(K)

#define STEP(UPD) {                                                         \
        { float t0A,t1A,t0B,t1B; eval2(pA,pB,cs[0],t0A,t1A,t0B,t1B); UPD(0) } \
        if (c1p) { float t0A,t1A,t0B,t1B; eval2(pA,pB,cs[1],t0A,t1A,t0B,t1B); UPD(1) } \
        if (c2p) { float t0A,t1A,t0B,t1B; eval2(pA,pB,cs[2],t0A,t1A,t0B,t1B); UPD(2) } \
        pA += PLANE; pB += PLANE; }

#define STEP2(UPD) {                                                        \
        const float* xA = pA + PLANE; const float* xB = pB + PLANE;         \
        { float t0A,t1A,t0B,t1B; eval2(pA,pB,cs[0],t0A,t1A,t0B,t1B); UPD(0) \
          eval2(xA,xB,cs[0],t0A,t1A,t0B,t1B); UPD(0) }                      \
        if (c1p) { float t0A,t1A,t0B,t1B;                                   \
                   eval2(pA,pB,cs[1],t0A,t1A,t0B,t1B); UPD(1)               \
                   eval2(xA,xB,cs[1],t0A,t1A,t0B,t1B); UPD(1) }             \
        if (c2p) { float t0A,t1A,t0B,t1B;                                   \
                   eval2(pA,pB,cs[2],t0A,t1A,t0B,t1B); UPD(2)               \
                   eval2(xA,xB,cs[2],t0A,t1A,t0B,t1B); UPD(2) }             \
        pA += 2 * PLANE; pB += 2 * PLANE; }

    const float* pA = fm + ((size_t)(b * Cc + cA)) * VOL + (size_t)s[0] * PLANE;
    const float* pB = fm + ((size_t)(b * Cc + cB)) * VOL + (size_t)s[0] * PLANE;
    int d = s[0];
    for (; d + 2 <= m1a[0]; d += 2) STEP2(UPD0)   // d-region 0 only
    for (; d < m1a[0]; ++d)         STEP(UPD0)
    for (; d < m0a[0]; ++d)         STEP(UPDB)    // overlap plane (n_d odd)
    for (; d + 2 <= e[0]; d += 2)   STEP2(UPD1)   // d-region 1 only
    for (; d < e[0]; ++d)           STEP(UPD1)

#undef STEP2
#undef STEP
#undef UPDB
#undef UPD1
#undef UPD0

    // Merge chunks with per-lane h-masks into 8 octants j = dr*4 + hr*2 + wr.
    float oA[8], oB[8];
#pragma unroll
    for (int i = 0; i < 8; ++i) { oA[i] = NI; oB[i] = NI; }
#define MERGE(K) {                                                          \
    oA[0]=fmaxf(oA[0], cs[K].h0 ? aA00[K] : NI);                            \
    oA[1]=fmaxf(oA[1], cs[K].h0 ? aA01[K] : NI);                            \
    oA[2]=fmaxf(oA[2], cs[K].h1 ? aA00[K] : NI);                            \
    oA[3]=fmaxf(oA[3], cs[K].h1 ? aA01[K] : NI);                            \
    oA[4]=fmaxf(oA[4], cs[K].h0 ? aA10[K] : NI);                            \
    oA[5]=fmaxf(oA[5], cs[K].h0 ? aA11[K] : NI);                            \
    oA[6]=fmaxf(oA[6], cs[K].h1 ? aA10[K] : NI);                            \
    oA[7]=fmaxf(oA[7], cs[K].h1 ? aA11[K] : NI);                            \
    oB[0]=fmaxf(oB[0], cs[K].h0 ? aB00[K] : NI);                            \
    oB[1]=fmaxf(oB[1], cs[K].h0 ? aB01[K] : NI);                            \
    oB[2]=fmaxf(oB[2], cs[K].h1 ? aB00[K] : NI);                            \
    oB[3]=fmaxf(oB[3], cs[K].h1 ? aB01[K] : NI);                            \
    oB[4]=fmaxf(oB[4], cs[K].h0 ? aB10[K] : NI);                            \
    oB[5]=fmaxf(oB[5], cs[K].h0 ? aB11[K] : NI);                            \
    oB[6]=fmaxf(oB[6], cs[K].h1 ? aB10[K] : NI);                            \
    oB[7]=fmaxf(oB[7], cs[K].h1 ? aB11[K] : NI); }
    MERGE(0)
    if (c1p) MERGE(1)
    if (c2p) MERGE(2)
#undef MERGE

    const float vA = oct_reduce(oA, lane);
    const float vB = oct_reduce(oB, lane);

    if (lane < 16) {
        const int   cc = (lane & 8) ? cB : cA;
        const float vv = (lane & 8) ? vB : vA;
        out[((size_t)bp * Cc + cc) * 8 + (lane & 7)] = vv;
    }
}

extern "C" void kernel_launch(void* const* d_in, const int* in_sizes, int n_in,
                              void* d_out, int out_size, void* d_ws, size_t ws_size,
                              hipStream_t stream) {
    const float* fm      = (const float*)d_in[0];
    const int*   corners = (const int*)d_in[1];
    const int*   scale   = (const int*)d_in[2];
    float*       out     = (float*)d_out;

    dim3 grid(Bc * Pc * 16);   // 4096 blocks: one wave per (proposal, ch-pair)
    dim3 block(256);
    crop_pool_kernel<<<grid, block, 0, stream>>>(fm, corners, scale, out);
}